// Round 1
// baseline (277.471 us; speedup 1.0000x reference)
//
#include <hip/hip_runtime.h>

#define B_  8
#define C_  32
#define H_  128
#define W_  128
#define CO_ 64
#define KK_ 9
#define HW_ (H_*W_)

__global__ __launch_bounds__(256) void dconv_fused(
    const float* __restrict__ x,
    const float* __restrict__ w_off,
    const float* __restrict__ b_off,
    const float* __restrict__ w_mod,
    const float* __restrict__ b_mod,
    const float* __restrict__ w_reg,
    float* __restrict__ out)
{
    const int tid = blockIdx.x * 256 + threadIdx.x;
    const int b  = tid / HW_;
    const int hw = tid % HW_;
    const int h  = hw / W_;
    const int w  = hw % W_;

    // ---------- stage 1: 3x3 conv producing 18 offset + 9 mask channels ----
    float oacc[27];
    #pragma unroll
    for (int j = 0; j < 18; ++j) oacc[j] = b_off[j];
    #pragma unroll
    for (int j = 0; j < 9; ++j)  oacc[18 + j] = b_mod[j];

    const float* xb = x + b * (C_ * HW_);

    for (int c = 0; c < C_; ++c) {
        float xv[9];
        #pragma unroll
        for (int t = 0; t < 9; ++t) {
            const int yy = h + t / 3 - 1;
            const int xx = w + t % 3 - 1;
            const bool ok = (yy >= 0) & (yy < H_) & (xx >= 0) & (xx < W_);
            xv[t] = ok ? xb[c * HW_ + yy * W_ + xx] : 0.0f;
        }
        const float* wo = w_off + c * 9;
        #pragma unroll
        for (int j = 0; j < 18; ++j) {
            #pragma unroll
            for (int t = 0; t < 9; ++t)
                oacc[j] = fmaf(wo[j * (C_ * 9) + t], xv[t], oacc[j]);
        }
        const float* wm = w_mod + c * 9;
        #pragma unroll
        for (int j = 0; j < 9; ++j) {
            #pragma unroll
            for (int t = 0; t < 9; ++t)
                oacc[18 + j] = fmaf(wm[j * (C_ * 9) + t], xv[t], oacc[18 + j]);
        }
    }

    // ---------- stage 2+3: bilinear sampling (validity+mask folded into
    // weights) and the o-c-kk einsum, 64 accumulators in registers ----------
    float acc[CO_];
    #pragma unroll
    for (int o = 0; o < CO_; ++o) acc[o] = 0.0f;

    #pragma unroll   // MUST unroll: oacc[] indexed by kk (avoid scratch)
    for (int kk = 0; kk < KK_; ++kk) {
        const int ky = kk / 3, kx = kk % 3;
        const float offy = fminf(fmaxf(oacc[kk * 2 + 0], -32.0f), 32.0f);
        const float offx = fminf(fmaxf(oacc[kk * 2 + 1], -32.0f), 32.0f);
        const float m = 2.0f / (1.0f + expf(-oacc[18 + kk]));

        const float py = offy + (float)(h - 1 + ky);
        const float px = offx + (float)(w - 1 + kx);
        const float y0f = floorf(py);
        const float x0f = floorf(px);
        const float dy = py - y0f;
        const float dx = px - x0f;
        const int y0 = (int)y0f, x0 = (int)x0f;
        const int y1 = y0 + 1,  x1 = x0 + 1;

        const bool vy0 = (y0 >= 0) & (y0 < H_);
        const bool vy1 = (y1 >= 0) & (y1 < H_);
        const bool vx0 = (x0 >= 0) & (x0 < W_);
        const bool vx1 = (x1 >= 0) & (x1 < W_);

        const float wm00 = (vy0 & vx0) ? (1.0f - dy) * (1.0f - dx) * m : 0.0f;
        const float wm01 = (vy0 & vx1) ? (1.0f - dy) * dx * m         : 0.0f;
        const float wm10 = (vy1 & vx0) ? dy * (1.0f - dx) * m         : 0.0f;
        const float wm11 = (vy1 & vx1) ? dy * dx * m                  : 0.0f;

        const int y0c = min(max(y0, 0), H_ - 1), y1c = min(max(y1, 0), H_ - 1);
        const int x0c = min(max(x0, 0), W_ - 1), x1c = min(max(x1, 0), W_ - 1);
        const int i00 = y0c * W_ + x0c;
        const int i01 = y0c * W_ + x1c;
        const int i10 = y1c * W_ + x0c;
        const int i11 = y1c * W_ + x1c;

        for (int c = 0; c < C_; ++c) {
            const float* xc = xb + c * HW_;
            const float s = wm00 * xc[i00] + wm01 * xc[i01]
                          + wm10 * xc[i10] + wm11 * xc[i11];
            const float* wr = w_reg + c * 9 + kk;   // uniform -> s_load
            #pragma unroll
            for (int o = 0; o < CO_; ++o)
                acc[o] = fmaf(wr[o * (C_ * 9)], s, acc[o]);
        }
    }

    float* ob = out + b * (CO_ * HW_) + hw;
    #pragma unroll
    for (int o = 0; o < CO_; ++o)
        ob[o * HW_] = acc[o];
}

extern "C" void kernel_launch(void* const* d_in, const int* in_sizes, int n_in,
                              void* d_out, int out_size, void* d_ws, size_t ws_size,
                              hipStream_t stream) {
    const float* x     = (const float*)d_in[0];
    const float* w_off = (const float*)d_in[1];
    const float* b_off = (const float*)d_in[2];
    const float* w_mod = (const float*)d_in[3];
    const float* b_mod = (const float*)d_in[4];
    const float* w_reg = (const float*)d_in[5];
    float* out = (float*)d_out;

    const int total = B_ * HW_;            // 131072 threads, 1 per pixel
    dconv_fused<<<total / 256, 256, 0, stream>>>(x, w_off, b_off, w_mod, b_mod,
                                                 w_reg, out);
}